// Round 14
// baseline (178.604 us; speedup 1.0000x reference)
//
#include <hip/hip_runtime.h>
#include <hip/hip_bf16.h>
#include <stdint.h>
#include <stddef.h>

typedef __bf16 bf16;
typedef __bf16 bf16x8 __attribute__((ext_vector_type(8)));
typedef float f32x4 __attribute__((ext_vector_type(4)));

#define BATCH 4096
#define KIH 7808          // Wih K
#define KTOT 7936         // 62 slots * 128 (h0 appended)
#define NG 512            // 4*LH gates
#define LH 128
#define HD 64
#define ED 128
#define SPLITK 4

// workspace layout (byte offsets)
#define OFF_WCAT 0u                 //  8,126,464  bf16 Wcat[512][7936]
#define OFF_GPART 8126464u          // 16,777,216  bf16 gpart[4][4096][512]
#define OFF_XT   24903680u          //  2,097,152  bf16 xtail[4096][256]
#define OFF_AB   27000832u          //     76,800  bf16 ab8[300][128]
#define OFF_MV   27077632u          //    230,400  bf16 mv8[900][128]
#define OFF_ADDR 27308032u          //  1,048,576  u32 addrs[4096][64]
#define OFF_W1B  28356608u          //     16,384  bf16 W1b[64][128]
#define OFF_W2B  28372992u          //     16,384  bf16 W2b[128][64]
#define OFF_WAB  28389376u          //      2,304  bf16 Wab[9][128]
#define OFF_NB   28391680u          //      2,048  f32 nbias[512]
// end: 28,393,728 B

// out layout: probs[B*9] | h1[B*128] | c1[B*128]
#define O_H1 (BATCH * 9)
#define O_C1 (BATCH * 9 + BATCH * LH)

// ---------------------------------------------------------------------------
typedef const __attribute__((address_space(1))) uint32_t* gas_ptr;
typedef __attribute__((address_space(3))) uint32_t* las_ptr;

__device__ __forceinline__ void async16(const void* g, void* l) {
    __builtin_amdgcn_global_load_lds((gas_ptr)g, (las_ptr)l, 16, 0, 0);
}

// ---------------------------------------------------------------------------
// Kernel 1: fused prep.
//   blocks 0..4095:      build_pre (per-row offsets + xtail = [num_pad|h0])
//   blocks 4096..4607:   convert_w + numproj weight folding + nbias
//   blocks 4608..5207:   convert_emb
//   block  5208:         plain bf16 copies of W1/W2/Wa
// ---------------------------------------------------------------------------
__global__ void prep(const int* __restrict__ ab_ids,
                     const int* __restrict__ mv_ids,
                     const float* __restrict__ numerical,
                     const float* __restrict__ h0,
                     const float* __restrict__ numW,
                     const float* __restrict__ numb,
                     const float* __restrict__ Wih,
                     const float* __restrict__ Whh,
                     const float* __restrict__ ab_emb,
                     const float* __restrict__ mv_emb,
                     const float* __restrict__ W1,
                     const float* __restrict__ W2,
                     const float* __restrict__ Wa,
                     uint8_t* __restrict__ ws) {
    const int bid = blockIdx.x;
    const int t = threadIdx.x;  // 0..255

    if (bid < BATCH) {
        // ---- build_pre: xtail + gather offsets ----
        bf16* xtail = (bf16*)(ws + OFF_XT);
        uint32_t* addrs = (uint32_t*)(ws + OFF_ADDR);
        const int b = bid;

        __shared__ int ids[60];
        if (t < 60) ids[t] = (t < 12) ? ab_ids[b * 12 + t] : mv_ids[b * 48 + (t - 12)];

        if (t < 128) {
            const float v = (t < 84) ? numerical[(size_t)b * 84 + t] : 0.f;
            xtail[(size_t)b * 256 + t] = (bf16)v;
        } else {
            const int tt = t - 128;
            xtail[(size_t)b * 256 + 128 + tt] = (bf16)h0[(size_t)b * LH + tt];
        }
        __syncthreads();

        if (t < 64) {
            uint32_t off;
            if (t < 12) off = OFF_AB + (uint32_t)ids[t] * 256u;
            else if (t < 60) off = OFF_MV + (uint32_t)ids[t] * 256u;
            else if (t == 60) off = OFF_XT + (uint32_t)b * 512u;
            else if (t == 61) off = OFF_XT + (uint32_t)b * 512u + 256u;
            else off = OFF_XT;  // unused slots 62,63
            addrs[(size_t)b * 64 + t] = off;
        }
    } else if (bid < BATCH + 512) {
        // ---- convert_w: cols [0,7680) direct; slot 60 = Wfold; then Whh ----
        bf16* Wcat = (bf16*)(ws + OFF_WCAT);
        float* nbias = (float*)(ws + OFF_NB);
        const int n = bid - BATCH;

        __shared__ float wrow[128];   // Wih[n][7680..7808)
        __shared__ float nbs[128];
        if (t < 128) wrow[t] = Wih[(size_t)n * KIH + 7680 + t];
        else nbs[t - 128] = numb[t - 128];
        __syncthreads();

        const float* src_ih = Wih + (size_t)n * KIH;
        bf16* dst = Wcat + (size_t)n * KTOT;
        for (int k4 = t; k4 < 1920; k4 += 256) {   // 7680/4
            const int k = k4 * 4;
            const float4 v = *(const float4*)(src_ih + k);
            bf16 o0 = (bf16)v.x, o1 = (bf16)v.y, o2 = (bf16)v.z, o3 = (bf16)v.w;
            dst[k] = o0; dst[k + 1] = o1; dst[k + 2] = o2; dst[k + 3] = o3;
        }
        if (t < 84) {
            // Wfold[n][t] = sum_e Wih[n][7680+e] * numW[e][t]
            float acc = 0.f;
#pragma unroll 4
            for (int e = 0; e < 128; ++e)
                acc += wrow[e] * numW[e * 84 + t];
            dst[7680 + t] = (bf16)acc;
        } else if (t < 128) {
            dst[7680 + t] = (bf16)0.f;     // padding cols (x is zero there too)
        } else {
            const int tt = t - 128;
            dst[KIH + tt] = (bf16)Whh[(size_t)n * LH + tt];
        }
        if (t == 255) {
            float a = 0.f;
#pragma unroll 4
            for (int e = 0; e < 128; ++e) a += wrow[e] * nbs[e];
            nbias[n] = a;
        }
    } else if (bid < BATCH + 512 + 600) {
        // ---- convert_emb ----
        bf16* ab8 = (bf16*)(ws + OFF_AB);
        bf16* mv8 = (bf16*)(ws + OFF_MV);
        const int i = (bid - BATCH - 512) * 256 + t;   // 0..153599
        if (i < 300 * 128) ab8[i] = (bf16)ab_emb[i];
        else if (i < 1200 * 128) mv8[i - 300 * 128] = (bf16)mv_emb[i - 300 * 128];
    } else {
        // ---- plain bf16 copies of MLP weights ----
        bf16* W1b = (bf16*)(ws + OFF_W1B);
        bf16* W2b = (bf16*)(ws + OFF_W2B);
        bf16* Wab = (bf16*)(ws + OFF_WAB);
        for (int e = t; e < 8192; e += 256) W1b[e] = (bf16)W1[e];
        for (int e = t; e < 8192; e += 256) W2b[e] = (bf16)W2[e];
        for (int e = t; e < 1152; e += 256) Wab[e] = (bf16)Wa[e];
    }
}

// ---------------------------------------------------------------------------
// Kernel 2: gpart[bz] = x @ Wcat.T partial  (x gathered on the fly)
// 128x128 block tile, BK=64, XOR-swizzled LDS, double-buffered, split-K=4.
// Intra-block K-split: 4 waves = 2 n-halves x 2 k-slices; wk-partials
// reduced through LDS.  Partials stored bf16 (plain stores).
// ---------------------------------------------------------------------------
__global__ __launch_bounds__(256, 2) void gemm_gates(
    const uint8_t* __restrict__ wsbase,
    const bf16* __restrict__ Wcat,
    const uint32_t* __restrict__ addrs,
    bf16* __restrict__ gpart) {
    __shared__ bf16 As[2][128 * 64];    // 2 x 16 KB
    __shared__ bf16 Bs[2][128 * 64];    // 2 x 16 KB
    __shared__ uint32_t adr[17][128];   // 8.5 KB

    const int tid = threadIdx.x;
    const int w = tid >> 6;       // wave 0..3
    const int lane = tid & 63;
    const int bm = blockIdx.x;    // 0..31
    const int bn = blockIdx.y;    // 0..3
    const int bz = blockIdx.z;    // 0..3
    const int kt_beg = bz * 31;
    const int kt_end = kt_beg + 31;

    // preload this block's (row, slot) offsets
    const int s0 = kt_beg >> 1;
    const int ns = ((kt_end - 1) >> 1) - s0 + 1;   // <= 17
    for (int i = tid; i < ns * 128; i += 256) {
        adr[i >> 7][i & 127] =
            addrs[(size_t)(bm * 128 + (i & 127)) * 64 + s0 + (i >> 7)];
    }

    const int r_l = lane >> 3;                  // staging row within 8-row group
    const int sc16 = ((lane & 7) ^ r_l) * 16;   // XOR-swizzled 16B chunk (bytes)

    const int wn = w & 1;         // n-half: cols wn*64 .. wn*64+63
    const int wk = w >> 1;        // k-slice: elems wk*32 .. wk*32+31 of each BK
    const int n0 = wn * 64;
    const int kk8 = wk * 4 + (lane >> 4);       // global column chunk for frags
    const int fl = lane & 15;

    f32x4 acc[8][4];
#pragma unroll
    for (int i = 0; i < 8; ++i)
#pragma unroll
        for (int j = 0; j < 4; ++j)
#pragma unroll
            for (int r = 0; r < 4; ++r) acc[i][j][r] = 0.f;

    __syncthreads();  // adr visible

    auto stage = [&](int kt, int pb) {
        const int k0 = kt * 64;
        const int sl = (kt >> 1) - s0;
        const int hb = (kt & 1) * 128;
#pragma unroll
        for (int j = 0; j < 4; ++j) {
            const int row = (w * 4 + j) * 8 + r_l;
            const uint8_t* gsrc = wsbase + adr[sl][row] + hb + sc16;
            async16(gsrc, (void*)&As[pb][((w * 4 + j) * 64 + lane) * 8]);
        }
#pragma unroll
        for (int j = 0; j < 4; ++j) {
            const int row = (w * 4 + j) * 8 + r_l;
            const bf16* gsrc = Wcat + (size_t)(bn * 128 + row) * KTOT + k0 + (sc16 >> 1);
            async16(gsrc, (void*)&Bs[pb][((w * 4 + j) * 64 + lane) * 8]);
        }
    };

    stage(kt_beg, 0);   // prologue into buffer 0

    for (int kt = kt_beg; kt < kt_end; ++kt) {
        const int pb = (kt - kt_beg) & 1;
        __syncthreads();
        if (kt + 1 < kt_end) stage(kt + 1, pb ^ 1);

        const bf16* Ab = &As[pb][0];
        const bf16* Bb = &Bs[pb][0];

        bf16x8 bfr[4];
#pragma unroll
        for (int tj = 0; tj < 4; ++tj) {
            const int n = n0 + tj * 16 + fl;
            bfr[tj] = *(const bf16x8*)&Bb[n * 64 + ((kk8 ^ (n & 7)) * 8)];
        }
#pragma unroll
        for (int ti = 0; ti < 8; ++ti) {
            const int m = ti * 16 + fl;
            const bf16x8 af = *(const bf16x8*)&Ab[m * 64 + ((kk8 ^ (m & 7)) * 8)];
#pragma unroll
            for (int tj = 0; tj < 4; ++tj)
                acc[ti][tj] = __builtin_amdgcn_mfma_f32_16x16x32_bf16(
                    af, bfr[tj], acc[ti][tj], 0, 0, 0);
        }
    }

    // ---- reduce wk-partials through LDS (As/Bs are dead now) ----
    __syncthreads();
    float* red = (wn == 0) ? (float*)&As[0][0] : (float*)&Bs[0][0];  // 32 KB each
    if (wk == 1) {
#pragma unroll
        for (int ti = 0; ti < 8; ++ti)
#pragma unroll
            for (int tj = 0; tj < 4; ++tj)
#pragma unroll
                for (int r = 0; r < 4; ++r)
                    red[((ti * 4 + tj) * 4 + r) * 64 + lane] = acc[ti][tj][r];
    }
    __syncthreads();

    if (wk == 0) {
        bf16* gdst = gpart + (size_t)bz * BATCH * NG;
        const int mlo = (lane >> 4) * 4;
#pragma unroll
        for (int ti = 0; ti < 8; ++ti)
#pragma unroll
            for (int tj = 0; tj < 4; ++tj) {
                const int mg = bm * 128 + ti * 16 + mlo;
                const int ng = bn * 128 + n0 + tj * 16 + fl;
                bf16* dst = gdst + (size_t)mg * NG + ng;
#pragma unroll
                for (int r = 0; r < 4; ++r)
                    dst[(size_t)r * NG] = (bf16)(
                        acc[ti][tj][r] + red[((ti * 4 + tj) * 4 + r) * 64 + lane]);
            }
    }
}

// ---------------------------------------------------------------------------
// Kernel 3: fused tail — split-K reduce + LSTM pointwise + MLP head +
// softmax + masked renorm.  2048 blocks x 256 threads, 2 rows/block
// (8 blocks/CU -> 32 waves/CU; no staging preamble, weights from L2).
// ---------------------------------------------------------------------------
__global__ void tail(const bf16* __restrict__ gpart,
                     const float* __restrict__ bih,
                     const float* __restrict__ bhh,
                     const float* __restrict__ nbias,
                     const float* __restrict__ c0,
                     const float* __restrict__ mask,
                     const bf16* __restrict__ W1b,
                     const float* __restrict__ b1,
                     const bf16* __restrict__ W2b,
                     const float* __restrict__ b2,
                     const bf16* __restrict__ Wab,
                     const float* __restrict__ ba,
                     float* __restrict__ out) {
    __shared__ float h1s[2][128];
    __shared__ float uS[2][64];
    __shared__ float fS[2][128];
    __shared__ float ls[2][12];

    const int t = threadIdx.x;
    const int b0 = blockIdx.x * 2;

    // ---- phase A: split-K reduce + LSTM pointwise (1 thread/(row,unit)) ----
    {
        const int b = b0 + (t >> 7);
        const int u = t & 127;
        float gv[4];
#pragma unroll
        for (int q = 0; q < 4; ++q)
            gv[q] = bih[q * 128 + u] + bhh[q * 128 + u] + nbias[q * 128 + u];
#pragma unroll
        for (int z = 0; z < SPLITK; ++z) {
            const bf16* gz = gpart + ((size_t)z * BATCH + b) * NG + u;
#pragma unroll
            for (int q = 0; q < 4; ++q) gv[q] += (float)gz[q * 128];
        }
        const float iv = 1.f / (1.f + __expf(-gv[0]));
        const float fv = 1.f / (1.f + __expf(-gv[1]));
        const float gg = tanhf(gv[2]);
        const float ov = 1.f / (1.f + __expf(-gv[3]));
        const float c1 = fv * c0[(size_t)b * LH + u] + iv * gg;
        const float h1 = ov * tanhf(c1);
        out[O_H1 + (size_t)b * LH + u] = h1;
        out[O_C1 + (size_t)b * LH + u] = c1;
        h1s[t >> 7][u] = h1;
    }
    __syncthreads();

    // ---- phase B1: u = relu(h1 @ W1^T + b1); threads 0..127 ----
    if (t < 128) {
        const int r = t >> 6, j = t & 63;
        float acc = b1[j];
        const bf16* wr = W1b + j * 128;
#pragma unroll 8
        for (int d = 0; d < 128; ++d)
            acc += h1s[r][d] * (float)wr[d];
        uS[r][j] = fmaxf(acc, 0.f);
    }
    __syncthreads();

    // ---- phase B2: feat = u @ W2^T + b2; all 256 threads ----
    {
        const int r = t >> 7, n = t & 127;
        float acc = b2[n];
        const bf16* wr = W2b + n * 64;
#pragma unroll 8
        for (int j = 0; j < 64; ++j)
            acc += uS[r][j] * (float)wr[j];
        fS[r][n] = acc;
    }
    __syncthreads();

    // ---- phase B3: logits; threads 0..17 ----
    if (t < 18) {
        const int r = t / 9, a = t % 9;
        float acc = ba[a];
        const bf16* wr = Wab + a * 128;
#pragma unroll 8
        for (int d = 0; d < 128; ++d)
            acc += fS[r][d] * (float)wr[d];
        ls[r][a] = acc;
    }
    __syncthreads();

    // ---- phase B4: softmax + masked renorm; threads 0..1 (one per row) ----
    if (t < 2) {
        const int b = b0 + t;
        float mx = ls[t][0];
#pragma unroll
        for (int a = 1; a < 9; ++a) mx = fmaxf(mx, ls[t][a]);
        float es[9], tot = 0.f, ms = 0.f;
#pragma unroll
        for (int a = 0; a < 9; ++a) {
            es[a] = __expf(ls[t][a] - mx);
            tot += es[a];
            ms += es[a] * mask[(size_t)b * 9 + a];
        }
#pragma unroll
        for (int a = 0; a < 9; ++a) {
            const float mv = mask[(size_t)b * 9 + a];
            out[(size_t)b * 9 + a] = (ms > 0.f) ? es[a] * mv / ms : es[a] / tot;
        }
    }
}

// ---------------------------------------------------------------------------
extern "C" void kernel_launch(void* const* d_in, const int* in_sizes, int n_in,
                              void* d_out, int out_size, void* d_ws, size_t ws_size,
                              hipStream_t stream) {
    const int* ab_ids = (const int*)d_in[0];
    const int* mv_ids = (const int*)d_in[1];
    const float* numerical = (const float*)d_in[2];
    const float* mask = (const float*)d_in[3];
    const float* h0 = (const float*)d_in[4];
    const float* c0 = (const float*)d_in[5];
    const float* ab_emb = (const float*)d_in[6];
    const float* mv_emb = (const float*)d_in[7];
    const float* numW = (const float*)d_in[8];
    const float* numb = (const float*)d_in[9];
    const float* Wih = (const float*)d_in[10];
    const float* Whh = (const float*)d_in[11];
    const float* bih = (const float*)d_in[12];
    const float* bhh = (const float*)d_in[13];
    const float* W1 = (const float*)d_in[14];
    const float* b1 = (const float*)d_in[15];
    const float* W2 = (const float*)d_in[16];
    const float* b2 = (const float*)d_in[17];
    const float* Wa = (const float*)d_in[18];
    const float* ba = (const float*)d_in[19];
    float* out = (float*)d_out;

    uint8_t* ws = (uint8_t*)d_ws;
    bf16* Wcat = (bf16*)(ws + OFF_WCAT);
    bf16* gpart = (bf16*)(ws + OFF_GPART);
    uint32_t* addrs = (uint32_t*)(ws + OFF_ADDR);
    bf16* W1b = (bf16*)(ws + OFF_W1B);
    bf16* W2b = (bf16*)(ws + OFF_W2B);
    bf16* Wab = (bf16*)(ws + OFF_WAB);
    float* nbias = (float*)(ws + OFF_NB);

    prep<<<BATCH + 512 + 600 + 1, 256, 0, stream>>>(
        ab_ids, mv_ids, numerical, h0, numW, numb, Wih, Whh, ab_emb, mv_emb,
        W1, W2, Wa, ws);
    gemm_gates<<<dim3(32, 4, SPLITK), 256, 0, stream>>>(ws, Wcat, addrs, gpart);
    tail<<<BATCH / 2, 256, 0, stream>>>(gpart, bih, bhh, nbias, c0, mask,
                                        W1b, b1, W2b, b2, Wab, ba, out);
}

// Round 15
// 167.423 us; speedup vs baseline: 1.0668x; 1.0668x over previous
//
#include <hip/hip_runtime.h>
#include <hip/hip_bf16.h>
#include <stdint.h>
#include <stddef.h>

typedef __bf16 bf16;
typedef __bf16 bf16x4 __attribute__((ext_vector_type(4)));
typedef __bf16 bf16x8 __attribute__((ext_vector_type(8)));
typedef float f32x4 __attribute__((ext_vector_type(4)));

#define BATCH 4096
#define KIH 7808          // Wih K
#define KTOT 7936         // 62 slots * 128 (h0 appended)
#define NG 512            // 4*LH gates
#define LH 128
#define HD 64
#define ED 128
#define SPLITK 4

// workspace layout (byte offsets)
#define OFF_WCAT 0u                 //  8,126,464  bf16 Wcat[512][7936]
#define OFF_GPART 8126464u          // 16,777,216  bf16 gpart[4][4096][512]
#define OFF_XT   24903680u          //  2,097,152  bf16 xtail[4096][256]
#define OFF_AB   27000832u          //     76,800  bf16 ab8[300][128]
#define OFF_MV   27077632u          //    230,400  bf16 mv8[900][128]
#define OFF_ADDR 27308032u          //  1,048,576  u32 addrs[4096][64]
#define OFF_H1B  28356608u          //  1,048,576  bf16 h1b[4096][128]
#define OFF_W1F  29405184u          //     16,384  bf16 W1 fragments
#define OFF_W2F  29421568u          //     16,384  bf16 W2 fragments
#define OFF_WAF  29437952u          //      4,096  bf16 Wa fragments
#define OFF_NB   29442048u          //      2,048  f32 nbias[512]
// end: 29,444,096 B

// out layout: probs[B*9] | h1[B*128] | c1[B*128]
#define O_H1 (BATCH * 9)
#define O_C1 (BATCH * 9 + BATCH * LH)

// prep grid partition
#define PREP_BP 2048                 // build_pre: 2 rows/block
#define PREP_CW (PREP_BP + 512)      // convert_w
#define PREP_CE (PREP_CW + 150)      // convert_emb (float4 x 256 x 150 = 153600)
#define PREP_TOT (PREP_CE + 1)       // + MLP fragment pack

// ---------------------------------------------------------------------------
typedef const __attribute__((address_space(1))) uint32_t* gas_ptr;
typedef __attribute__((address_space(3))) uint32_t* las_ptr;

__device__ __forceinline__ void async16(const void* g, void* l) {
    __builtin_amdgcn_global_load_lds((gas_ptr)g, (las_ptr)l, 16, 0, 0);
}

// ---------------------------------------------------------------------------
// Kernel 1: fused prep.
//   blocks [0, 2048):        build_pre, 2 rows/block (offsets + xtail)
//   blocks [2048, 2560):     convert_w + numproj folding + nbias
//   blocks [2560, 2710):     convert_emb (vectorized)
//   block  2710:             pack MLP weight fragments
// ---------------------------------------------------------------------------
__global__ void prep(const int* __restrict__ ab_ids,
                     const int* __restrict__ mv_ids,
                     const float* __restrict__ numerical,
                     const float* __restrict__ h0,
                     const float* __restrict__ numW,
                     const float* __restrict__ numb,
                     const float* __restrict__ Wih,
                     const float* __restrict__ Whh,
                     const float* __restrict__ ab_emb,
                     const float* __restrict__ mv_emb,
                     const float* __restrict__ W1,
                     const float* __restrict__ W2,
                     const float* __restrict__ Wa,
                     uint8_t* __restrict__ ws) {
    const int bid = blockIdx.x;
    const int t = threadIdx.x;  // 0..255

    if (bid < PREP_BP) {
        // ---- build_pre: 2 rows per block; half-block (128 thr) per row ----
        bf16* xtail = (bf16*)(ws + OFF_XT);
        uint32_t* addrs = (uint32_t*)(ws + OFF_ADDR);
        const int h = t >> 7;            // row half 0/1
        const int th = t & 127;
        const int b = bid * 2 + h;

        __shared__ int ids[2][60];
        if (th < 60)
            ids[h][th] = (th < 12) ? ab_ids[b * 12 + th]
                                   : mv_ids[b * 48 + (th - 12)];

        const float v = (th < 84) ? numerical[(size_t)b * 84 + th] : 0.f;
        xtail[(size_t)b * 256 + th] = (bf16)v;
        xtail[(size_t)b * 256 + 128 + th] = (bf16)h0[(size_t)b * LH + th];
        __syncthreads();

        if (th < 64) {
            uint32_t off;
            if (th < 12) off = OFF_AB + (uint32_t)ids[h][th] * 256u;
            else if (th < 60) off = OFF_MV + (uint32_t)ids[h][th] * 256u;
            else if (th == 60) off = OFF_XT + (uint32_t)b * 512u;
            else if (th == 61) off = OFF_XT + (uint32_t)b * 512u + 256u;
            else off = OFF_XT;  // unused slots 62,63
            addrs[(size_t)b * 64 + th] = off;
        }
    } else if (bid < PREP_CW) {
        // ---- convert_w: cols [0,7680) direct; slot 60 = Wfold; then Whh ----
        bf16* Wcat = (bf16*)(ws + OFF_WCAT);
        float* nbias = (float*)(ws + OFF_NB);
        const int n = bid - PREP_BP;

        __shared__ float wrow[128];   // Wih[n][7680..7808)
        __shared__ float nbs[128];
        if (t < 128) wrow[t] = Wih[(size_t)n * KIH + 7680 + t];
        else nbs[t - 128] = numb[t - 128];
        __syncthreads();

        const float* src_ih = Wih + (size_t)n * KIH;
        bf16* dst = Wcat + (size_t)n * KTOT;
        for (int k4 = t; k4 < 1920; k4 += 256) {   // 7680/4
            const int k = k4 * 4;
            const float4 v = *(const float4*)(src_ih + k);
            bf16x4 o = {(bf16)v.x, (bf16)v.y, (bf16)v.z, (bf16)v.w};
            *(bf16x4*)(dst + k) = o;
        }
        if (t < 84) {
            // Wfold[n][t] = sum_e Wih[n][7680+e] * numW[e][t]
            float acc = 0.f;
#pragma unroll 4
            for (int e = 0; e < 128; ++e)
                acc += wrow[e] * numW[e * 84 + t];
            dst[7680 + t] = (bf16)acc;
        } else if (t < 128) {
            dst[7680 + t] = (bf16)0.f;     // padding cols (x is zero there too)
        } else {
            const int tt = t - 128;
            dst[KIH + tt] = (bf16)Whh[(size_t)n * LH + tt];
        }
        if (t == 255) {
            float a = 0.f;
#pragma unroll 4
            for (int e = 0; e < 128; ++e) a += wrow[e] * nbs[e];
            nbias[n] = a;
        }
    } else if (bid < PREP_CE) {
        // ---- convert_emb: 4 elems/thread, float4 -> bf16x4 ----
        bf16* ab8 = (bf16*)(ws + OFF_AB);
        bf16* mv8 = (bf16*)(ws + OFF_MV);
        const int i = ((bid - PREP_CW) * 256 + t) * 4;   // 0..153596
        const bool isab = i < 300 * 128;
        const float4 v = isab ? *(const float4*)(ab_emb + i)
                              : *(const float4*)(mv_emb + (i - 300 * 128));
        bf16x4 o = {(bf16)v.x, (bf16)v.y, (bf16)v.z, (bf16)v.w};
        if (isab) *(bf16x4*)(ab8 + i) = o;
        else *(bf16x4*)(mv8 + (i - 300 * 128)) = o;
    } else {
        // ---- pack MLP weight fragments (B-frag: lane n=l&15, k=(l>>4)*8+j) --
        bf16* W1f = (bf16*)(ws + OFF_W1F);
        bf16* W2f = (bf16*)(ws + OFF_W2F);
        bf16* Waf = (bf16*)(ws + OFF_WAF);
        for (int e = t; e < 8192; e += 256) {     // W1 (64x128), fid = nt*4+kt
            const int j = e & 7, ln = (e >> 3) & 63, fid = e >> 9;
            const int kt = fid & 3, nt = fid >> 2;
            const int n = nt * 16 + (ln & 15);
            const int k = kt * 32 + (ln >> 4) * 8 + j;
            W1f[e] = (bf16)W1[n * 128 + k];
        }
        for (int e = t; e < 8192; e += 256) {     // W2 (128x64), fid = nt*2+kt
            const int j = e & 7, ln = (e >> 3) & 63, fid = e >> 9;
            const int kt = fid & 1, nt = fid >> 1;
            const int n = nt * 16 + (ln & 15);
            const int k = kt * 32 + (ln >> 4) * 8 + j;
            W2f[e] = (bf16)W2[n * 64 + k];
        }
        for (int e = t; e < 2048; e += 256) {     // Wa (9x128 zero-padded)
            const int j = e & 7, ln = (e >> 3) & 63, kt = e >> 9;
            const int n = ln & 15;
            const int k = kt * 32 + (ln >> 4) * 8 + j;
            Waf[e] = (n < 9) ? (bf16)Wa[n * 128 + k] : (bf16)0.f;
        }
    }
}

// ---------------------------------------------------------------------------
// Kernel 2: gpart[bz] = x @ Wcat.T partial  (x gathered on the fly)
// 128x128 block tile, BK=64, XOR-swizzled LDS, double-buffered, split-K=4.
// Intra-block K-split: 4 waves = 2 n-halves x 2 k-slices; wk-partials
// reduced through LDS.  Partials stored bf16 (plain stores).
// ---------------------------------------------------------------------------
__global__ __launch_bounds__(256, 2) void gemm_gates(
    const uint8_t* __restrict__ wsbase,
    const bf16* __restrict__ Wcat,
    const uint32_t* __restrict__ addrs,
    bf16* __restrict__ gpart) {
    __shared__ bf16 As[2][128 * 64];    // 2 x 16 KB
    __shared__ bf16 Bs[2][128 * 64];    // 2 x 16 KB
    __shared__ uint32_t adr[17][128];   // 8.5 KB

    const int tid = threadIdx.x;
    const int w = tid >> 6;       // wave 0..3
    const int lane = tid & 63;
    const int bm = blockIdx.x;    // 0..31
    const int bn = blockIdx.y;    // 0..3
    const int bz = blockIdx.z;    // 0..3
    const int kt_beg = bz * 31;
    const int kt_end = kt_beg + 31;

    // preload this block's (row, slot) offsets
    const int s0 = kt_beg >> 1;
    const int ns = ((kt_end - 1) >> 1) - s0 + 1;   // <= 17
    for (int i = tid; i < ns * 128; i += 256) {
        adr[i >> 7][i & 127] =
            addrs[(size_t)(bm * 128 + (i & 127)) * 64 + s0 + (i >> 7)];
    }

    const int r_l = lane >> 3;                  // staging row within 8-row group
    const int sc16 = ((lane & 7) ^ r_l) * 16;   // XOR-swizzled 16B chunk (bytes)

    const int wn = w & 1;         // n-half: cols wn*64 .. wn*64+63
    const int wk = w >> 1;        // k-slice: elems wk*32 .. wk*32+31 of each BK
    const int n0 = wn * 64;
    const int kk8 = wk * 4 + (lane >> 4);       // global column chunk for frags
    const int fl = lane & 15;

    f32x4 acc[8][4];
#pragma unroll
    for (int i = 0; i < 8; ++i)
#pragma unroll
        for (int j = 0; j < 4; ++j)
#pragma unroll
            for (int r = 0; r < 4; ++r) acc[i][j][r] = 0.f;

    __syncthreads();  // adr visible

    auto stage = [&](int kt, int pb) {
        const int k0 = kt * 64;
        const int sl = (kt >> 1) - s0;
        const int hb = (kt & 1) * 128;
#pragma unroll
        for (int j = 0; j < 4; ++j) {
            const int row = (w * 4 + j) * 8 + r_l;
            const uint8_t* gsrc = wsbase + adr[sl][row] + hb + sc16;
            async16(gsrc, (void*)&As[pb][((w * 4 + j) * 64 + lane) * 8]);
        }
#pragma unroll
        for (int j = 0; j < 4; ++j) {
            const int row = (w * 4 + j) * 8 + r_l;
            const bf16* gsrc = Wcat + (size_t)(bn * 128 + row) * KTOT + k0 + (sc16 >> 1);
            async16(gsrc, (void*)&Bs[pb][((w * 4 + j) * 64 + lane) * 8]);
        }
    };

    stage(kt_beg, 0);   // prologue into buffer 0

    for (int kt = kt_beg; kt < kt_end; ++kt) {
        const int pb = (kt - kt_beg) & 1;
        __syncthreads();
        if (kt + 1 < kt_end) stage(kt + 1, pb ^ 1);

        const bf16* Ab = &As[pb][0];
        const bf16* Bb = &Bs[pb][0];

        bf16x8 bfr[4];
#pragma unroll
        for (int tj = 0; tj < 4; ++tj) {
            const int n = n0 + tj * 16 + fl;
            bfr[tj] = *(const bf16x8*)&Bb[n * 64 + ((kk8 ^ (n & 7)) * 8)];
        }
#pragma unroll
        for (int ti = 0; ti < 8; ++ti) {
            const int m = ti * 16 + fl;
            const bf16x8 af = *(const bf16x8*)&Ab[m * 64 + ((kk8 ^ (m & 7)) * 8)];
#pragma unroll
            for (int tj = 0; tj < 4; ++tj)
                acc[ti][tj] = __builtin_amdgcn_mfma_f32_16x16x32_bf16(
                    af, bfr[tj], acc[ti][tj], 0, 0, 0);
        }
    }

    // ---- reduce wk-partials through LDS (As/Bs are dead now) ----
    __syncthreads();
    float* red = (wn == 0) ? (float*)&As[0][0] : (float*)&Bs[0][0];  // 32 KB each
    if (wk == 1) {
#pragma unroll
        for (int ti = 0; ti < 8; ++ti)
#pragma unroll
            for (int tj = 0; tj < 4; ++tj)
#pragma unroll
                for (int r = 0; r < 4; ++r)
                    red[((ti * 4 + tj) * 4 + r) * 64 + lane] = acc[ti][tj][r];
    }
    __syncthreads();

    if (wk == 0) {
        bf16* gdst = gpart + (size_t)bz * BATCH * NG;
        const int mlo = (lane >> 4) * 4;
#pragma unroll
        for (int ti = 0; ti < 8; ++ti)
#pragma unroll
            for (int tj = 0; tj < 4; ++tj) {
                const int mg = bm * 128 + ti * 16 + mlo;
                const int ng = bn * 128 + n0 + tj * 16 + fl;
                bf16* dst = gdst + (size_t)mg * NG + ng;
#pragma unroll
                for (int r = 0; r < 4; ++r)
                    dst[(size_t)r * NG] = (bf16)(
                        acc[ti][tj][r] + red[((ti * 4 + tj) * 4 + r) * 64 + lane]);
            }
    }
}

// ---------------------------------------------------------------------------
// Kernel 3: reduce split-K partials + LSTM pointwise.
// 2048 blocks x 256 threads; 2 rows/block, 1 thread per LSTM unit.
// ---------------------------------------------------------------------------
__global__ void reduce_lstm(const bf16* __restrict__ gpart,
                            const float* __restrict__ bih,
                            const float* __restrict__ bhh,
                            const float* __restrict__ nbias,
                            const float* __restrict__ c0,
                            float* __restrict__ out,
                            bf16* __restrict__ h1b) {
    const int t = threadIdx.x;
    const int b = blockIdx.x * 2 + (t >> 7);
    const int u = t & 127;

    float gv[4];
#pragma unroll
    for (int q = 0; q < 4; ++q)
        gv[q] = bih[q * 128 + u] + bhh[q * 128 + u] + nbias[q * 128 + u];
#pragma unroll
    for (int z = 0; z < SPLITK; ++z) {
        const bf16* gz = gpart + ((size_t)z * BATCH + b) * NG + u;
#pragma unroll
        for (int q = 0; q < 4; ++q) gv[q] += (float)gz[q * 128];
    }

    const float iv = 1.f / (1.f + __expf(-gv[0]));
    const float fv = 1.f / (1.f + __expf(-gv[1]));
    const float gg = tanhf(gv[2]);
    const float ov = 1.f / (1.f + __expf(-gv[3]));
    const float c1 = fv * c0[(size_t)b * LH + u] + iv * gg;
    const float h1 = ov * tanhf(c1);

    out[O_H1 + (size_t)b * LH + u] = h1;
    out[O_C1 + (size_t)b * LH + u] = c1;
    h1b[(size_t)b * LH + u] = (bf16)h1;
}

// ---------------------------------------------------------------------------
// Kernel 4: MLP head, 1 wave per block, 16 rows/block, 256 blocks.
// Weight B-fragments read straight global->VGPR from pre-packed L2-resident
// arrays; LDS only for u/feat C->A relayout.
// ---------------------------------------------------------------------------
__global__ __launch_bounds__(64) void mlp_head(
    const bf16* __restrict__ h1b, const float* __restrict__ mask,
    const bf16* __restrict__ W1f, const bf16* __restrict__ W2f,
    const bf16* __restrict__ Waf,
    const float* __restrict__ b1, const float* __restrict__ b2,
    const float* __restrict__ ba,
    float* __restrict__ out) {
    __shared__ bf16 uS[16 * 64];     // 2 KB
    __shared__ bf16 fS[16 * 128];    // 4 KB

    const int lane = threadIdx.x;    // 0..63
    const int b0 = blockIdx.x * 16;
    const int nl = lane & 15, kg = lane >> 4;

    bf16x8 ah[4];
#pragma unroll
    for (int kt = 0; kt < 4; ++kt)
        ah[kt] = *(const bf16x8*)&h1b[(size_t)(b0 + nl) * 128 + kt * 32 + kg * 8];

    // ---- stage 1: u = relu(h1 @ W1^T + b1)  (16x64) ----
#pragma unroll
    for (int nt = 0; nt < 4; ++nt) {
        f32x4 a = {0.f, 0.f, 0.f, 0.f};
#pragma unroll
        for (int kt = 0; kt < 4; ++kt)
            a = __builtin_amdgcn_mfma_f32_16x16x32_bf16(
                ah[kt], *(const bf16x8*)&W1f[((nt * 4 + kt) * 64 + lane) * 8],
                a, 0, 0, 0);
        const int n = nt * 16 + nl;
        const float bb = b1[n];
#pragma unroll
        for (int r = 0; r < 4; ++r)
            uS[(kg * 4 + r) * 64 + n] = (bf16)fmaxf(a[r] + bb, 0.f);
    }
    __syncthreads();

    bf16x8 au[2];
#pragma unroll
    for (int kt = 0; kt < 2; ++kt)
        au[kt] = *(const bf16x8*)&uS[nl * 64 + kt * 32 + kg * 8];

    // ---- stage 2: feat = u @ W2^T + b2  (16x128) ----
#pragma unroll
    for (int nt = 0; nt < 8; ++nt) {
        f32x4 a = {0.f, 0.f, 0.f, 0.f};
#pragma unroll
        for (int kt = 0; kt < 2; ++kt)
            a = __builtin_amdgcn_mfma_f32_16x16x32_bf16(
                au[kt], *(const bf16x8*)&W2f[((nt * 2 + kt) * 64 + lane) * 8],
                a, 0, 0, 0);
        const int n = nt * 16 + nl;
        const float bb = b2[n];
#pragma unroll
        for (int r = 0; r < 4; ++r)
            fS[(kg * 4 + r) * 128 + n] = (bf16)(a[r] + bb);
    }
    __syncthreads();

    bf16x8 afr[4];
#pragma unroll
    for (int kt = 0; kt < 4; ++kt)
        afr[kt] = *(const bf16x8*)&fS[nl * 128 + kt * 32 + kg * 8];

    // ---- stage 3: logits = feat @ Wa^T + ba  (16x16, 9 valid) ----
    f32x4 lg4 = {0.f, 0.f, 0.f, 0.f};
#pragma unroll
    for (int kt = 0; kt < 4; ++kt)
        lg4 = __builtin_amdgcn_mfma_f32_16x16x32_bf16(
            afr[kt], *(const bf16x8*)&Waf[(kt * 64 + lane) * 8], lg4, 0, 0, 0);

    const float bav = (nl < 9) ? ba[nl] : 0.f;

    // ---- softmax + masked renorm; row m = kg*4+r, action = nl ----
#pragma unroll
    for (int r = 0; r < 4; ++r) {
        const int b = b0 + kg * 4 + r;
        float lg = (nl < 9) ? lg4[r] + bav : -1e30f;
        float mx = lg;
#pragma unroll
        for (int off = 1; off < 16; off <<= 1)
            mx = fmaxf(mx, __shfl_xor(mx, off, 64));
        const float e = (nl < 9) ? __expf(lg - mx) : 0.f;
        const float mv = (nl < 9) ? mask[(size_t)b * 9 + nl] : 0.f;
        float tot = e, ms = e * mv;
#pragma unroll
        for (int off = 1; off < 16; off <<= 1) {
            tot += __shfl_xor(tot, off, 64);
            ms += __shfl_xor(ms, off, 64);
        }
        if (nl < 9)
            out[(size_t)b * 9 + nl] = (ms > 0.f) ? e * mv / ms : e / tot;
    }
}

// ---------------------------------------------------------------------------
extern "C" void kernel_launch(void* const* d_in, const int* in_sizes, int n_in,
                              void* d_out, int out_size, void* d_ws, size_t ws_size,
                              hipStream_t stream) {
    const int* ab_ids = (const int*)d_in[0];
    const int* mv_ids = (const int*)d_in[1];
    const float* numerical = (const float*)d_in[2];
    const float* mask = (const float*)d_in[3];
    const float* h0 = (const float*)d_in[4];
    const float* c0 = (const float*)d_in[5];
    const float* ab_emb = (const float*)d_in[6];
    const float* mv_emb = (const float*)d_in[7];
    const float* numW = (const float*)d_in[8];
    const float* numb = (const float*)d_in[9];
    const float* Wih = (const float*)d_in[10];
    const float* Whh = (const float*)d_in[11];
    const float* bih = (const float*)d_in[12];
    const float* bhh = (const float*)d_in[13];
    const float* W1 = (const float*)d_in[14];
    const float* b1 = (const float*)d_in[15];
    const float* W2 = (const float*)d_in[16];
    const float* b2 = (const float*)d_in[17];
    const float* Wa = (const float*)d_in[18];
    const float* ba = (const float*)d_in[19];
    float* out = (float*)d_out;

    uint8_t* ws = (uint8_t*)d_ws;
    bf16* Wcat = (bf16*)(ws + OFF_WCAT);
    bf16* gpart = (bf16*)(ws + OFF_GPART);
    uint32_t* addrs = (uint32_t*)(ws + OFF_ADDR);
    bf16* h1b = (bf16*)(ws + OFF_H1B);
    bf16* W1f = (bf16*)(ws + OFF_W1F);
    bf16* W2f = (bf16*)(ws + OFF_W2F);
    bf16* Waf = (bf16*)(ws + OFF_WAF);
    float* nbias = (float*)(ws + OFF_NB);

    prep<<<PREP_TOT, 256, 0, stream>>>(
        ab_ids, mv_ids, numerical, h0, numW, numb, Wih, Whh, ab_emb, mv_emb,
        W1, W2, Wa, ws);
    gemm_gates<<<dim3(32, 4, SPLITK), 256, 0, stream>>>(ws, Wcat, addrs, gpart);
    reduce_lstm<<<BATCH / 2, 256, 0, stream>>>(gpart, bih, bhh, nbias, c0,
                                               out, h1b);
    mlp_head<<<BATCH / 16, 64, 0, stream>>>(h1b, mask, W1f, W2f, Waf,
                                            b1, b2, ba, out);
}